// Round 4
// baseline (563.290 us; speedup 1.0000x reference)
//
#include <hip/hip_runtime.h>

#define NV 9
#define FIN 5
#define FHID 3
#define SPB 64                 // samples per chunk (== block size, one sample/thread)
#define A_ELEMS (NV*NV)        // 81
#define H_ELEMS (NV*FIN)       // 45
#define A_CHUNK (SPB*A_ELEMS)  // 5184 floats = 20736 B
#define H_CHUNK (SPB*H_ELEMS)  // 2880 floats = 11520 B
#define SLOTS_PER_CU 5         // 5 x 32256 B = 157.5 KB of the 160 KB LDS pool
#define PERSIST_BLOCKS (256*SLOTS_PER_CU)  // 1280

// One wave moves 16 B/lane = 1024 B per instruction, global -> LDS, async.
// LDS dest is wave-uniform base + lane*16 (per-lane ptr must be linear in lane).
__device__ __forceinline__ void load_lds16(const float* g, float* l) {
    __builtin_amdgcn_global_load_lds(
        (const __attribute__((address_space(1))) unsigned int*)g,
        (__attribute__((address_space(3))) unsigned int*)l, 16, 0, 0);
}

// Stage one 64-sample chunk (A: 20.25 KB, h0: 11.25 KB) into the LDS buffer.
__device__ __forceinline__ void stage_chunk(const float* __restrict__ gA,
                                            const float* __restrict__ gH,
                                            float* bA, float* bH,
                                            int tid, int cnt)
{
    if (cnt == SPB) {
        // A: 20 full 1-KB wave transfers + 256 B tail (lanes 0..15)
#pragma unroll
        for (int j = 0; j < 20; j++)
            load_lds16(gA + j * 256 + tid * 4, bA + j * 256 + tid * 4);
        if (tid < 16)
            load_lds16(gA + 20 * 256 + tid * 4, bA + 20 * 256 + tid * 4);
        // h0: 11 full transfers + 256 B tail
#pragma unroll
        for (int j = 0; j < 11; j++)
            load_lds16(gH + j * 256 + tid * 4, bH + j * 256 + tid * 4);
        if (tid < 16)
            load_lds16(gH + 11 * 256 + tid * 4, bH + 11 * 256 + tid * 4);
    } else {
        // generic tail fallback (never hit at B=1e6: 1e6 % 64 == 0). Plain
        // loads + ds_writes; drained by the lgkmcnt(0) in the loop-top wait.
        const int nA = cnt * A_ELEMS;
        for (int i = tid; i < nA; i += SPB) bA[i] = gA[i];
        const int nH = cnt * H_ELEMS;
        for (int i = tid; i < nH; i += SPB) bH[i] = gH[i];
    }
}

// Persistent single-buffer pipeline: 5 blocks/CU (LDS-limited), each iteration
//   drain -> consume LDS to registers -> ISSUE next chunk's DMA -> compute.
// The next chunk's 32 KB delivery overlaps this chunk's register compute, and
// five independent slots per CU keep aggregate HBM demand continuous.
__global__ __launch_bounds__(64) void gcn_persist_kernel(
    const float* __restrict__ A, const float* __restrict__ h0,
    const float* __restrict__ W, const float* __restrict__ fc_w,
    const float* __restrict__ fc_b, float* __restrict__ out, int Btot)
{
    __shared__ float sA[A_CHUNK];   // raw global layout (DMA dest must be linear)
    __shared__ float sH[H_CHUNK];

    const int tid = threadIdx.x;
    const int nChunks = (Btot + SPB - 1) / SPB;
    int c = blockIdx.x;
    if (c >= nChunks) return;
    const int stride = gridDim.x;

    // tiny params: uniform -> scalar loads, cached
    float Wr[FIN * FHID];
#pragma unroll
    for (int k = 0; k < FIN * FHID; k++) Wr[k] = W[k];
    const float fw0 = fc_w[0], fw1 = fc_w[1], fw2 = fc_w[2];
    const float fb = fc_b[0];

    // prologue: stage first chunk
    {
        const long long base = (long long)c * SPB;
        const int cnt = (Btot - (int)base < SPB) ? (Btot - (int)base) : SPB;
        stage_chunk(A + base * A_ELEMS, h0 + base * H_ELEMS, sA, sH, tid, cnt);
    }

    for (; c < nChunks; c += stride) {
        // Chunk ready. vmcnt covers global_load_lds (compiler does not model its
        // LDS write); lgkmcnt covers the fallback path's ds_writes.
        asm volatile("s_waitcnt vmcnt(0) lgkmcnt(0)" ::: "memory");

        const long long base = (long long)c * SPB;
        const int cnt = (Btot - (int)base < SPB) ? (Btot - (int)base) : SPB;
        const bool active = tid < cnt;

        // ---- consume LDS: A row -> registers; h0 row -> G (pre-dinv) ----
        float a[A_ELEMS];
        float G[NV * FHID];
        if (active) {
            const float* Ai = sA + tid * A_ELEMS;  // stride 81 words (odd) -> free 2-way alias
            const float* Hi = sH + tid * H_ELEMS;  // stride 45 words (odd)
#pragma unroll
            for (int i = 0; i < A_ELEMS; i++) a[i] = Ai[i];
#pragma unroll
            for (int u = 0; u < NV; u++) {
                float hr[FIN];
#pragma unroll
                for (int f = 0; f < FIN; f++) hr[f] = Hi[u * FIN + f];
#pragma unroll
                for (int h = 0; h < FHID; h++) {
                    float acc = 0.0f;
#pragma unroll
                    for (int f = 0; f < FIN; f++) acc += hr[f] * Wr[f * FHID + h];
                    G[u * FHID + h] = acc;
                }
            }
        }

        // All ds_reads of this chunk must COMPLETE before the DMA below can
        // overwrite the buffer ("memory" clobber pins the ds_reads above this).
        asm volatile("s_waitcnt lgkmcnt(0)" ::: "memory");

        // ---- issue next chunk's DMA into the SAME buffer; its ~32 KB delivery
        // overlaps the register-only compute below ----
        const int cn = c + stride;
        if (cn < nChunks) {
            const long long nb = (long long)cn * SPB;
            const int ncnt = (Btot - (int)nb < SPB) ? (Btot - (int)nb) : SPB;
            stage_chunk(A + nb * A_ELEMS, h0 + nb * H_ELEMS, sA, sH, tid, ncnt);
        }

        // ---- register-only compute ----
        if (active) {
            // deg[j] = 1 + sum_i A[i][j] (column sums of A + I)
            float deg[NV];
#pragma unroll
            for (int j = 0; j < NV; j++) deg[j] = 1.0f;
#pragma unroll
            for (int r = 0; r < NV; r++) {
#pragma unroll
                for (int j = 0; j < NV; j++) deg[j] += a[r * NV + j];
            }
            float dinv[NV];
#pragma unroll
            for (int j = 0; j < NV; j++) dinv[j] = 1.0f / sqrtf(deg[j]);

            // fold dinv[u] into G
#pragma unroll
            for (int u = 0; u < NV; u++) {
#pragma unroll
                for (int h = 0; h < FHID; h++) G[u * FHID + h] *= dinv[u];
            }

            // h2[h] = sum_v relu( dinv[v] * sum_u AI[v][u] * G[u][h] )
            float h2_0 = 0.0f, h2_1 = 0.0f, h2_2 = 0.0f;
#pragma unroll
            for (int v = 0; v < NV; v++) {
                float a0 = 0.0f, a1 = 0.0f, a2 = 0.0f;
#pragma unroll
                for (int u = 0; u < NV; u++) {
                    const float aiv = a[v * NV + u] + ((u == v) ? 1.0f : 0.0f);
                    a0 += aiv * G[u * FHID + 0];
                    a1 += aiv * G[u * FHID + 1];
                    a2 += aiv * G[u * FHID + 2];
                }
                const float dv = dinv[v];
                h2_0 += fmaxf(a0 * dv, 0.0f);
                h2_1 += fmaxf(a1 * dv, 0.0f);
                h2_2 += fmaxf(a2 * dv, 0.0f);
            }

            out[base + tid] = h2_0 * fw0 + h2_1 * fw1 + h2_2 * fw2 + fb;
        }
    }
}

extern "C" void kernel_launch(void* const* d_in, const int* in_sizes, int n_in,
                              void* d_out, int out_size, void* d_ws, size_t ws_size,
                              hipStream_t stream) {
    const float* A    = (const float*)d_in[0];
    const float* h0   = (const float*)d_in[1];
    const float* W    = (const float*)d_in[2];
    const float* fc_w = (const float*)d_in[3];
    const float* fc_b = (const float*)d_in[4];
    float* out = (float*)d_out;

    const int Btot = in_sizes[0] / A_ELEMS;  // 1,000,000
    const int nChunks = (Btot + SPB - 1) / SPB;
    const int grid = nChunks < PERSIST_BLOCKS ? nChunks : PERSIST_BLOCKS;

    gcn_persist_kernel<<<grid, SPB, 0, stream>>>(A, h0, W, fc_w, fc_b, out, Btot);
}

// Round 6
// 524.477 us; speedup vs baseline: 1.0740x; 1.0740x over previous
//
#include <hip/hip_runtime.h>

#define NV 9
#define FIN 5
#define FHID 3
#define SPB 64                 // samples per block (== block size, one sample/thread)
#define A_ELEMS (NV*NV)        // 81 floats = 324 B per sample
#define H_ELEMS (NV*FIN)       // 45 floats = 180 B per sample
#define A_CHUNK (SPB*A_ELEMS)  // 5184 floats = 20736 B = 20*1KB + 256B

// One wave moves 16 B/lane = 1024 B per instruction, global -> LDS, async.
// LDS dest is wave-uniform base + lane*16 (per-lane ptr must be linear in lane).
__device__ __forceinline__ void load_lds16(const float* g, float* l) {
    __builtin_amdgcn_global_load_lds(
        (const __attribute__((address_space(1))) unsigned int*)g,
        (__attribute__((address_space(3))) unsigned int*)l, 16, 0, 0);
}

// 16-byte load safe at 4-byte alignment (h0 rows are 180 B apart).
__device__ __forceinline__ float4 ld16(const float* p) {
    float4 v;
    __builtin_memcpy(&v, p, 16);
    return v;
}

// R0 structure (non-persistent, 1 wave/block, DMA-stage A, drain, compute, exit)
// with two changes:
//  - h0 bypasses LDS: per-thread direct dwordx4 loads, ISSUED while the A-DMA
//    delivers, so their latency hides under the A drain. h0 is per-thread-private
//    data; LDS bought nothing but a round-trip.
//  - LDS/block drops 31.5 KB -> 20.25 KB: 7 concurrent blocks/CU instead of 5
//    (+40% independent HBM streams, shorter per-stream delivery).
__global__ __launch_bounds__(64) void gcn_hybrid_kernel(
    const float* __restrict__ A, const float* __restrict__ h0,
    const float* __restrict__ W, const float* __restrict__ fc_w,
    const float* __restrict__ fc_b, float* __restrict__ out, int Btot)
{
    __shared__ float sA[A_CHUNK];  // raw global layout (DMA dest must be linear)

    const int tid = threadIdx.x;
    const long long base = (long long)blockIdx.x * SPB;
    const int cnt = (Btot - (int)base < SPB) ? (Btot - (int)base) : SPB;
    const float* gA = A + base * A_ELEMS;  // 20736 B * blockIdx -> 16B aligned

    if (cnt == SPB) {
        // ---- async global->LDS staging of A: 20 full 1-KB wave transfers + 256B tail ----
#pragma unroll
        for (int j = 0; j < 20; j++)
            load_lds16(gA + j * 256 + tid * 4, sA + j * 256 + tid * 4);
        if (tid < 16)
            load_lds16(gA + 20 * 256 + tid * 4, sA + 20 * 256 + tid * 4);
    } else {
        // generic fallback (never hit at B=1e6: 1e6 % 64 == 0)
        const int nA = cnt * A_ELEMS;
        for (int i = tid; i < nA; i += SPB) sA[i] = gA[i];
    }

    // ---- h0 direct loads into registers, in the DMA's latency shadow ----
    const bool active = tid < cnt;
    float h[H_ELEMS];
    if (active) {
        const float* Hi = h0 + (base + tid) * H_ELEMS;
#pragma unroll
        for (int j = 0; j < 11; j++) {
            float4 v = ld16(Hi + 4 * j);                 // pure register renaming below:
            h[4*j+0] = v.x; h[4*j+1] = v.y;              // no extra instructions, no
            h[4*j+2] = v.z; h[4*j+3] = v.w;              // wait until first real use
        }
        h[44] = Hi[44];
    }

    // ---- tiny params (uniform -> scalar s_loads, lgkm counter, cached) ----
    float Wr[FIN * FHID];
#pragma unroll
    for (int k = 0; k < FIN * FHID; k++) Wr[k] = W[k];
    const float fw0 = fc_w[0], fw1 = fc_w[1], fw2 = fc_w[2];
    const float fb = fc_b[0];

    // RACE FIX: compiler does not model global_load_lds's LDS write, and a
    // single-wave block lets it weaken __syncthreads — force the drain.
    // (Also covers the fallback path's ds_writes via lgkmcnt.)
    asm volatile("s_waitcnt vmcnt(0) lgkmcnt(0)" ::: "memory");
    __syncthreads();

    if (!active) return;

    const float* Ai = sA + tid * A_ELEMS;  // stride 81 words (odd) -> only free 2-way alias

    // Pull A into registers once (81 ds_read), reuse for both passes.
    float a[A_ELEMS];
#pragma unroll
    for (int i = 0; i < A_ELEMS; i++) a[i] = Ai[i];

    // deg[j] = 1 + sum_i A[i][j]  (column sums of A + I)
    float deg[NV];
#pragma unroll
    for (int j = 0; j < NV; j++) deg[j] = 1.0f;
#pragma unroll
    for (int r = 0; r < NV; r++) {
#pragma unroll
        for (int j = 0; j < NV; j++) deg[j] += a[r * NV + j];
    }
    float dinv[NV];
#pragma unroll
    for (int j = 0; j < NV; j++) dinv[j] = 1.0f / sqrtf(deg[j]);

    // G[u][h] = dinv[u] * (h0[u,:] . W[:,h])   (h0 from registers)
    float G[NV * FHID];
#pragma unroll
    for (int u = 0; u < NV; u++) {
#pragma unroll
        for (int hh = 0; hh < FHID; hh++) {
            float acc = 0.0f;
#pragma unroll
            for (int f = 0; f < FIN; f++) acc += h[u * FIN + f] * Wr[f * FHID + hh];
            G[u * FHID + hh] = dinv[u] * acc;
        }
    }

    // h2[h] = sum_v relu( dinv[v] * sum_u AI[v][u] * G[u][h] )
    float h2_0 = 0.0f, h2_1 = 0.0f, h2_2 = 0.0f;
#pragma unroll
    for (int v = 0; v < NV; v++) {
        float a0 = 0.0f, a1 = 0.0f, a2 = 0.0f;
#pragma unroll
        for (int u = 0; u < NV; u++) {
            const float aiv = a[v * NV + u] + ((u == v) ? 1.0f : 0.0f);
            a0 += aiv * G[u * FHID + 0];
            a1 += aiv * G[u * FHID + 1];
            a2 += aiv * G[u * FHID + 2];
        }
        const float dv = dinv[v];
        h2_0 += fmaxf(a0 * dv, 0.0f);
        h2_1 += fmaxf(a1 * dv, 0.0f);
        h2_2 += fmaxf(a2 * dv, 0.0f);
    }

    out[base + tid] = h2_0 * fw0 + h2_1 * fw1 + h2_2 * fw2 + fb;
}

extern "C" void kernel_launch(void* const* d_in, const int* in_sizes, int n_in,
                              void* d_out, int out_size, void* d_ws, size_t ws_size,
                              hipStream_t stream) {
    const float* A    = (const float*)d_in[0];
    const float* h0   = (const float*)d_in[1];
    const float* W    = (const float*)d_in[2];
    const float* fc_w = (const float*)d_in[3];
    const float* fc_b = (const float*)d_in[4];
    float* out = (float*)d_out;

    const int Btot = in_sizes[0] / A_ELEMS;  // 1,000,000
    const int grid = (Btot + SPB - 1) / SPB;

    gcn_hybrid_kernel<<<grid, SPB, 0, stream>>>(A, h0, W, fc_w, fc_b, out, Btot);
}